// Round 5
// baseline (1229.481 us; speedup 1.0000x reference)
//
#include <hip/hip_runtime.h>
#include <hip/hip_bf16.h>
#include <math.h>

// B=8192, D=512, V=64, E=8, hidden (1024,512,256)
// All matmuls as bf16 MFMA with hi/lo split (3 products): K'=3K sections
// 0: Ahi*Bhi, 1: Alo*Bhi, 2: Ahi*Blo.  A: [M][2K] hi|lo, Bt: [N][2K] hi|lo.
// Round 5: 2 phases per K-tile (32-MFMA clusters, half the barriers),
// LDS-staged vectorized epilogue, gate softmax fused into gate-L2 slice.

typedef short bf16x8 __attribute__((ext_vector_type(8)));
typedef float f32x4 __attribute__((ext_vector_type(4)));

#define AS1 __attribute__((address_space(1)))
#define AS3 __attribute__((address_space(3)))
#define SCHED0 __builtin_amdgcn_sched_barrier(0)
#define SBAR __builtin_amdgcn_s_barrier()

__device__ __forceinline__ ushort f2bf(float x){
  union { float f; unsigned u; } v; v.f = x;
  unsigned r = v.u + 0x7fffu + ((v.u >> 16) & 1u);
  return (ushort)(r >> 16);
}
__device__ __forceinline__ float bf2f(ushort h){
  union { unsigned u; float f; } v; v.u = ((unsigned)h) << 16; return v.f;
}
__device__ __forceinline__ float elu_f(float x){
  return x > 0.f ? x : expm1f(x);
}

// ---- unified prep: activations ----
struct AJob { const float* X; ushort* A; int total, K; };
__global__ void prep_act_all(AJob j0, AJob j1, int t0){
  int i = blockIdx.x * 256 + threadIdx.x;
  AJob J; int idx;
  if (i < t0){ J = j0; idx = i; }
  else { J = j1; idx = i - t0; if (idx >= J.total) return; }
  int row = idx / J.K, k = idx - row * J.K;
  float x = J.X[idx];
  ushort hi = f2bf(x);
  ushort lo = f2bf(x - bf2f(hi));
  size_t base = (size_t)row * (size_t)(2 * J.K);
  J.A[base + k] = hi;
  J.A[base + J.K + k] = lo;
}

// ---- unified prep: weights f32 [E][K][N] -> [E][N][2K] bf16 hi|lo ----
struct WJob { const float* W; ushort* Bt; int K, N, nb, nk, blkStart; };
struct WJobs { WJob j[6]; int njobs; };
__global__ void prep_w_all(WJobs jobs){
  __shared__ float tile[32][33];
  int b = blockIdx.x;
  int ji = 0;
  while (ji + 1 < jobs.njobs && b >= jobs.j[ji + 1].blkStart) ji++;
  WJob J = jobs.j[ji];
  int rem = b - J.blkStart;
  int x = rem % J.nb; rem /= J.nb;
  int y = rem % J.nk; int e = rem / J.nk;
  const float* w = J.W + (size_t)e * J.K * J.N;
  ushort* bt = J.Bt + (size_t)e * J.N * 2 * J.K;
  int n0 = x * 32, k0 = y * 32;
  for (int i = threadIdx.y; i < 32; i += 8)
    tile[i][threadIdx.x] = w[(size_t)(k0 + i) * J.N + n0 + threadIdx.x];
  __syncthreads();
  for (int jj = threadIdx.y; jj < 32; jj += 8){
    float v = tile[threadIdx.x][jj];
    ushort hi = f2bf(v);
    ushort lo = f2bf(v - bf2f(hi));
    size_t base = (size_t)(n0 + jj) * (size_t)(2 * J.K);
    bt[base + k0 + threadIdx.x] = hi;
    bt[base + J.K + k0 + threadIdx.x] = lo;
  }
}

// ---- descriptor-batched 256x256 GEMM, 2 phases/K-tile ----
// mode 0: C = split bf16 [M][2N].
// mode 2: ret[row*8+eidx] = sum_col elu(acc+bias)*w3[col] + rbp[0]
// mode 3: gate fused: wts row = softmax(h2row @ w3[256][8] + rbp[8]) -> ret
struct Slice {
  const ushort* A; const ushort* Bt; const float* bias; void* C;
  const float* w3; const float* rbp; float* ret;
  int N, K, log2gx, mode, blkStart, eidx;
};
struct SliceArr { Slice s[9]; int nz; };

__global__ __launch_bounds__(512, 2) void gemm8p(SliceArr args){
  __shared__ __align__(16) ushort As[2][256][64];   // 64KB
  __shared__ __align__(16) ushort Bs[2][256][64];   // 64KB
  __shared__ float red[4][256];                     // 4KB (mode-2 reduce)

  // XCD-chunked bijective swizzle (grids here are multiples of 8)
  const int nwg  = gridDim.x;
  const int orig = blockIdx.x;
  const int wg   = (orig & 7) * (nwg >> 3) + (orig >> 3);

  int z = 0;
  while (z + 1 < args.nz && wg >= args.s[z + 1].blkStart) z++;
  const Slice sl = args.s[z];
  const int rem = wg - sl.blkStart;
  const int gxm = (1 << sl.log2gx) - 1;
  const int bx  = rem & gxm;
  const int by  = rem >> sl.log2gx;

  const ushort* __restrict__ Ag = sl.A;
  const ushort* __restrict__ Bg = sl.Bt;
  const int K = sl.K;

  const int tid  = threadIdx.x;
  const int lane = tid & 63;
  const int wave = tid >> 6;
  const int wr = wave >> 2;                     // 0..1 (M half)
  const int wc = wave & 3;                      // 0..3 (N quarter)
  const int rowBase = by * 256;
  const int colBase = bx * 256;
  const int KB = K >> 6;
  const int NT = 3 * KB;
  const int lr = lane & 15;
  const int lk = (lane >> 4) << 3;
  const int swzR = (lr & 7) << 3;
  const size_t strideK2 = (size_t)(2 * K);

  const int rowS = tid >> 3;
  const int swzS = ((tid >> 3) & 7) << 3;
  const int colS = ((tid & 7) << 3) ^ swzS;

  auto stageHalf = [&](int t, int hx, int buf){
    int tt = (t < NT) ? t : (NT - 1);           // clamp: dead-but-safe
    int sec = (tt >= 2 * KB) ? 2 : (tt >= KB) ? 1 : 0;
    int inner = tt - sec * KB;
    bool isB = hx < 2;
    int h = hx & 1;
    int ko = (isB ? ((sec == 2) ? K : 0) : ((sec == 1) ? K : 0)) + (inner << 6);
    const ushort* gbase = isB ? Bg : Ag;
    int rb = (isB ? colBase : rowBase) + h * 128;
    char* lb = (char*)(isB ? &Bs[buf][0][0] : &As[buf][0][0]) + h * 16384;
    #pragma unroll
    for (int j = 0; j < 2; j++){
      const ushort* src = gbase + (size_t)(rb + j * 64 + rowS) * strideK2 + ko + colS;
      __builtin_amdgcn_global_load_lds((const AS1 void*)src,
                                       (AS3 void*)(lb + j * 8192 + tid * 16), 16, 0, 0);
    }
  };

  bf16x8 a[8], b[8];
  auto loadA = [&](int buf, int h){
    #pragma unroll
    for (int m = 0; m < 4; m++)
      #pragma unroll
      for (int ks = 0; ks < 2; ks++)
        a[m * 2 + ks] = *(const bf16x8*)&As[buf][wr * 128 + h * 64 + m * 16 + lr][(ks * 32 + lk) ^ swzR];
  };
  auto loadB = [&](int buf, int h){
    #pragma unroll
    for (int n2 = 0; n2 < 2; n2++)
      #pragma unroll
      for (int ks = 0; ks < 2; ks++)
        b[h * 4 + n2 * 2 + ks] = *(const bf16x8*)&Bs[buf][wc * 64 + h * 32 + n2 * 16 + lr][(ks * 32 + lk) ^ swzR];
  };

  f32x4 acc[8][4];
  #pragma unroll
  for (int m = 0; m < 8; m++)
    #pragma unroll
    for (int n = 0; n < 4; n++)
      acc[m][n] = (f32x4){0.f, 0.f, 0.f, 0.f};

  auto mfmaH = [&](int mh){
    #pragma unroll
    for (int m = 0; m < 4; m++)
      #pragma unroll
      for (int n = 0; n < 4; n++)
        #pragma unroll
        for (int ks = 0; ks < 2; ks++)
          acc[mh * 4 + m][n] = __builtin_amdgcn_mfma_f32_16x16x32_bf16(
              a[m * 2 + ks], b[n * 2 + ks], acc[mh * 4 + m][n], 0, 0, 0);
  };

  // prologue: tile0 fully + {B0,B1,A0} of tile1
  #pragma unroll
  for (int hx = 0; hx < 4; hx++) stageHalf(0, hx, 0);
  #pragma unroll
  for (int hx = 0; hx < 3; hx++) stageHalf(1, hx, 1);
  asm volatile("s_waitcnt vmcnt(6)" ::: "memory");
  SCHED0; SBAR; SCHED0;

  for (int t = 0; t < NT; ++t){
    const int cur = t & 1;
    // ---- phA: full B + A-half0 reads | stage t+1.A1 | 32 MFMA (mh=0)
    loadB(cur, 0); loadB(cur, 1); loadA(cur, 0);
    stageHalf(t + 1, 3, cur ^ 1);
    SCHED0; SBAR;
    asm volatile("s_waitcnt lgkmcnt(0)" ::: "memory"); SCHED0;
    __builtin_amdgcn_s_setprio(1); mfmaH(0); __builtin_amdgcn_s_setprio(0);
    SCHED0; SBAR; SCHED0;
    // ---- phB: A-half1 reads | stage t+2.{B0,B1,A0} | vmcnt(6) | 32 MFMA (mh=1)
    loadA(cur, 1);
    stageHalf(t + 2, 0, cur);
    stageHalf(t + 2, 1, cur);
    stageHalf(t + 2, 2, cur);
    asm volatile("s_waitcnt vmcnt(6)" ::: "memory");
    SCHED0; SBAR;
    asm volatile("s_waitcnt lgkmcnt(0)" ::: "memory"); SCHED0;
    __builtin_amdgcn_s_setprio(1); mfmaH(1); __builtin_amdgcn_s_setprio(0);
    SCHED0; SBAR; SCHED0;
  }

  // ---- epilogue (C/D layout: col=lane&15, row=(lane>>4)*4+reg) ----
  const int ce = colBase + wc * 64 + lr;

  if (sl.mode == 2){
    // fused final expert layer: ret[row] = sum_col elu(h2)*w3[col] + b3
    __syncthreads();
    #pragma unroll
    for (int m = 0; m < 8; m++){
      float p4[4] = {0.f, 0.f, 0.f, 0.f};
      #pragma unroll
      for (int n = 0; n < 4; n++){
        int col = ce + n * 16;
        float bv = sl.bias[col];
        float wv = sl.w3[col];
        #pragma unroll
        for (int r = 0; r < 4; r++)
          p4[r] += elu_f(acc[m][n][r] + bv) * wv;
      }
      #pragma unroll
      for (int r = 0; r < 4; r++){
        #pragma unroll
        for (int s = 8; s > 0; s >>= 1) p4[r] += __shfl_xor(p4[r], s, 64);
      }
      if ((lane & 15) == 0){
        int hig = lane >> 4;
        #pragma unroll
        for (int r = 0; r < 4; r++)
          red[wc][wr * 128 + m * 16 + hig * 4 + r] = p4[r];
      }
    }
    __syncthreads();
    if (tid < 256){
      float s4 = red[0][tid] + red[1][tid] + red[2][tid] + red[3][tid];
      sl.ret[(size_t)(rowBase + tid) * 8 + sl.eidx] = s4 + sl.rbp[0];
    }
    return;
  }

  // modes 0 / 3: LDS-staged per-m-slice epilogue (aliases Bs after drain)
  asm volatile("s_waitcnt vmcnt(0)" ::: "memory");
  __syncthreads();
  float* epi = (float*)&Bs[0][0][0];            // 32*259*4 = 33KB <= 64KB
  const int EW = 259;
  const int N = sl.N;

  #pragma unroll 1
  for (int m = 0; m < 8; m++){
    // write phase: elu(acc+bias) -> epi[32][256]
    {
      int srb = wr * 16 + ((lane >> 4) << 2);
      #pragma unroll
      for (int n = 0; n < 4; n++){
        int col = ce + n * 16;
        float bv = sl.bias[col];
        int cb = col - colBase;
        #pragma unroll
        for (int r = 0; r < 4; r++)
          epi[(srb + r) * EW + cb] = elu_f(acc[m][n][r] + bv);
      }
    }
    __syncthreads();
    if (sl.mode == 0){
      int sr = tid & 31, ch = tid >> 5;
      int grow = rowBase + m * 16 + (sr & 15) + ((sr >> 4) << 7);
      int gcol = colBase + ch * 16;
      float vv[16];
      #pragma unroll
      for (int j = 0; j < 16; j++) vv[j] = epi[sr * EW + ch * 16 + j];
      bf16x8 hv0, hv1, lv0, lv1;
      #pragma unroll
      for (int j = 0; j < 8; j++){
        ushort h = f2bf(vv[j]);
        hv0[j] = (short)h; lv0[j] = (short)f2bf(vv[j] - bf2f(h));
      }
      #pragma unroll
      for (int j = 0; j < 8; j++){
        ushort h = f2bf(vv[8 + j]);
        hv1[j] = (short)h; lv1[j] = (short)f2bf(vv[8 + j] - bf2f(h));
      }
      ushort* Cc = (ushort*)sl.C;
      size_t rb = (size_t)grow * (size_t)(2 * N);
      *(bf16x8*)&Cc[rb + gcol] = hv0;
      *(bf16x8*)&Cc[rb + gcol + 8] = hv1;
      *(bf16x8*)&Cc[rb + N + gcol] = lv0;
      *(bf16x8*)&Cc[rb + N + gcol + 8] = lv1;
    } else {
      // mode 3: gate row-dot with w3[256][8] + softmax -> ret (wts)
      int rr = tid >> 4, cc = tid & 15;
      float p[8];
      #pragma unroll
      for (int j = 0; j < 8; j++) p[j] = 0.f;
      #pragma unroll 4
      for (int c2 = 0; c2 < 16; c2++){
        float x = epi[rr * EW + cc * 16 + c2];
        const float* g3 = sl.w3 + (size_t)(cc * 16 + c2) * 8;
        #pragma unroll
        for (int j = 0; j < 8; j++) p[j] += x * g3[j];
      }
      #pragma unroll
      for (int j = 0; j < 8; j++){
        #pragma unroll
        for (int s = 8; s > 0; s >>= 1) p[j] += __shfl_xor(p[j], s, 64);
      }
      if (cc == 0){
        float mx = -1e30f;
        #pragma unroll
        for (int j = 0; j < 8; j++){ p[j] += sl.rbp[j]; mx = fmaxf(mx, p[j]); }
        float sum = 0.f;
        #pragma unroll
        for (int j = 0; j < 8; j++){ p[j] = expf(p[j] - mx); sum += p[j]; }
        float inv = 1.f / sum;
        int grow = rowBase + m * 16 + (rr & 15) + ((rr >> 4) << 7);
        #pragma unroll
        for (int j = 0; j < 8; j++)
          sl.ret[(size_t)grow * 8 + j] = p[j] * inv;
      }
    }
    __syncthreads();
  }
}

// ---- final combine ----
__global__ void combine(const float* __restrict__ wts, const float* __restrict__ ret,
                        float* __restrict__ out){
  int i = blockIdx.x * blockDim.x + threadIdx.x;
  if (i >= 8192) return;
  float s = 0.f;
  #pragma unroll
  for (int j = 0; j < 8; j++) s += wts[(size_t)i * 8 + j] * ret[(size_t)i * 8 + j];
  out[i] = s;
}

extern "C" void kernel_launch(void* const* d_in, const int* in_sizes, int n_in,
                              void* d_out, int out_size, void* d_ws, size_t ws_size,
                              hipStream_t stream){
  const float* obs  = (const float*)d_in[0];
  const float* code = (const float*)d_in[1];
  const float* ew0  = (const float*)d_in[2];
  const float* eb0  = (const float*)d_in[3];
  const float* ew1  = (const float*)d_in[4];
  const float* eb1  = (const float*)d_in[5];
  const float* ew2  = (const float*)d_in[6];
  const float* eb2  = (const float*)d_in[7];
  const float* ew3  = (const float*)d_in[8];
  const float* eb3  = (const float*)d_in[9];
  const float* gw0  = (const float*)d_in[10];
  const float* gb0  = (const float*)d_in[11];
  const float* gw1  = (const float*)d_in[12];
  const float* gb1  = (const float*)d_in[13];
  const float* gw2  = (const float*)d_in[14];
  const float* gb2  = (const float*)d_in[15];
  const float* gw3  = (const float*)d_in[16];
  const float* gb3  = (const float*)d_in[17];
  (void)in_sizes; (void)n_in; (void)out_size;

  char* ws = (char*)d_ws;
  size_t off = 0;
  auto alloc = [&](size_t bytes) -> void* {
    void* p = ws + off;
    off += (bytes + 255) & ~(size_t)255;
    return p;
  };
  ushort* A_obs  = (ushort*)alloc(8192ull * 1024 * 2);
  ushort* A_code = (ushort*)alloc(8192ull * 128 * 2);
  ushort* B_ew0  = (ushort*)alloc(8ull * 1024 * 1024 * 2);
  ushort* B_ew1  = (ushort*)alloc(8ull * 512 * 2048 * 2);
  ushort* B_ew2  = (ushort*)alloc(8ull * 256 * 1024 * 2);
  ushort* B_gw0  = (ushort*)alloc(1024ull * 128 * 2);
  ushort* B_gw1  = (ushort*)alloc(512ull * 2048 * 2);
  ushort* B_gw2  = (ushort*)alloc(256ull * 1024 * 2);
  float*  wts    = (float*)alloc(8192ull * 8 * 4);
  float*  ret    = (float*)alloc(8192ull * 8 * 4);
  const size_t fixed = off;

  const size_t sl0b = 8192ull * 2048 * 2;   // h0 split bf16 (32MiB)
  const size_t sl1b = 8192ull * 1024 * 2;   // h1 split bf16 (16MiB)
  const size_t pairB = sl0b + sl1b;

  int G = 0;
  {
    const int cand[5] = {8, 4, 3, 2, 1};
    for (int ci = 0; ci < 5; ci++)
      if (fixed + (size_t)(cand[ci] + 1) * pairB <= ws_size){ G = cand[ci]; break; }
  }
  const bool gateFirst = (G == 0);
  const int ns = gateFirst ? 1 : (G + 1);
  ushort* h0buf = (ushort*)alloc((size_t)ns * sl0b);
  ushort* h1buf = (ushort*)alloc((size_t)ns * sl1b);
  const size_t sl0e = 8192ull * 2048;
  const size_t sl1e = 8192ull * 1024;
  const int gsl = ns - 1;
  ushort* h0g = h0buf + (size_t)gsl * sl0e;
  ushort* h1g = h1buf + (size_t)gsl * sl1e;

  // prep (2 dispatches)
  {
    AJob j0 = {obs,  A_obs,  8192 * 512, 512};
    AJob j1 = {code, A_code, 8192 * 64,  64};
    int t0 = 8192 * 512;
    prep_act_all<<<dim3((t0 + j1.total + 255) / 256), 256, 0, stream>>>(j0, j1, t0);

    WJobs wj; wj.njobs = 6;
    int bs = 0;
    auto addW = [&](int i, const float* W, ushort* Bt, int K, int N, int E){
      wj.j[i] = {W, Bt, K, N, N / 32, K / 32, bs};
      bs += E * (N / 32) * (K / 32);
    };
    addW(0, ew0, B_ew0, 512, 1024, 8);
    addW(1, ew1, B_ew1, 1024, 512, 8);
    addW(2, ew2, B_ew2, 512, 256, 8);
    addW(3, gw0, B_gw0, 64, 1024, 1);
    addW(4, gw1, B_gw1, 1024, 512, 1);
    addW(5, gw2, B_gw2, 512, 256, 1);
    prep_w_all<<<dim3(bs), dim3(32, 8), 0, stream>>>(wj);
  }

  auto runGroup = [&](int e0, int cnt, bool withGate){
    SliceArr sa; int nb;
    // L0
    nb = 0; sa.nz = cnt + (withGate ? 1 : 0);
    for (int i = 0; i < cnt; i++){ int e = e0 + i;
      sa.s[i] = {A_obs, B_ew0 + (size_t)e * 1024 * 1024, eb0 + e * 1024,
                 h0buf + (size_t)i * sl0e, nullptr, nullptr, nullptr,
                 1024, 512, 2, 0, nb, 0};
      nb += 4 * 32;
    }
    if (withGate){
      sa.s[cnt] = {A_code, B_gw0, gb0, h0g, nullptr, nullptr, nullptr,
                   1024, 64, 2, 0, nb, 0};
      nb += 4 * 32;
    }
    for (int i = sa.nz; i < 9; i++) sa.s[i] = sa.s[0];
    gemm8p<<<dim3(nb), 512, 0, stream>>>(sa);
    // L1
    nb = 0;
    for (int i = 0; i < cnt; i++){ int e = e0 + i;
      sa.s[i] = {h0buf + (size_t)i * sl0e, B_ew1 + (size_t)e * 512 * 2048, eb1 + e * 512,
                 h1buf + (size_t)i * sl1e, nullptr, nullptr, nullptr,
                 512, 1024, 1, 0, nb, 0};
      nb += 2 * 32;
    }
    if (withGate){
      sa.s[cnt] = {h0g, B_gw1, gb1, h1g, nullptr, nullptr, nullptr,
                   512, 1024, 1, 0, nb, 0};
      nb += 2 * 32;
    }
    gemm8p<<<dim3(nb), 512, 0, stream>>>(sa);
    // L2: experts fused-returns (mode 2); gate fused softmax (mode 3)
    nb = 0;
    for (int i = 0; i < cnt; i++){ int e = e0 + i;
      sa.s[i] = {h1buf + (size_t)i * sl1e, B_ew2 + (size_t)e * 256 * 1024, eb2 + e * 256,
                 nullptr, ew3 + (size_t)e * 256, eb3 + e, ret,
                 256, 512, 0, 2, nb, e};
      nb += 32;
    }
    if (withGate){
      sa.s[cnt] = {h1g, B_gw2, gb2, nullptr, gw3, gb3, wts,
                   256, 512, 0, 3, nb, 0};
      nb += 32;
    }
    gemm8p<<<dim3(nb), 512, 0, stream>>>(sa);
  };

  if (gateFirst){
    SliceArr sa; sa.nz = 1;
    sa.s[0] = {A_code, B_gw0, gb0, h0g, nullptr, nullptr, nullptr, 1024, 64, 2, 0, 0, 0};
    for (int i = 1; i < 9; i++) sa.s[i] = sa.s[0];
    gemm8p<<<dim3(128), 512, 0, stream>>>(sa);
    sa.s[0] = {h0g, B_gw1, gb1, h1g, nullptr, nullptr, nullptr, 512, 1024, 1, 0, 0, 0};
    gemm8p<<<dim3(64), 512, 0, stream>>>(sa);
    sa.s[0] = {h1g, B_gw2, gb2, nullptr, gw3, gb3, wts, 256, 512, 0, 3, 0, 0};
    gemm8p<<<dim3(32), 512, 0, stream>>>(sa);
    for (int e = 0; e < 8; e++) runGroup(e, 1, false);
  } else {
    bool first = true;
    for (int e0 = 0; e0 < 8; ){
      int cnt = (8 - e0 < G) ? (8 - e0) : G;
      runGroup(e0, cnt, first);
      first = false;
      e0 += cnt;
    }
  }

  combine<<<dim3(8192 / 256), 256, 0, stream>>>(wts, ret, (float*)d_out);
}

// Round 7
// 984.133 us; speedup vs baseline: 1.2493x; 1.2493x over previous
//
#include <hip/hip_runtime.h>
#include <hip/hip_bf16.h>
#include <math.h>

// B=8192, D=512, V=64, E=8, hidden (1024,512,256)
// All matmuls as bf16 MFMA with hi/lo split (3 products): K'=3K sections
// 0: Ahi*Bhi, 1: Alo*Bhi, 2: Ahi*Blo.  A: [M][2K] hi|lo, Bt: [N][2K] hi|lo.
// Round 7: R6's deep-staging 4-phase pipeline with the half-partition fix:
// read-halves now equal stage-halves (rows h*128..h*128+127), so staging
// tile t+2 into the in-use buffer is race-free and every load has >=1
// full K-tile of latency cover before its counted vmcnt(8).

typedef short bf16x8 __attribute__((ext_vector_type(8)));
typedef float f32x4 __attribute__((ext_vector_type(4)));

#define AS1 __attribute__((address_space(1)))
#define AS3 __attribute__((address_space(3)))
#define SCHED0 __builtin_amdgcn_sched_barrier(0)
#define SBAR __builtin_amdgcn_s_barrier()

__device__ __forceinline__ ushort f2bf(float x){
  union { float f; unsigned u; } v; v.f = x;
  unsigned r = v.u + 0x7fffu + ((v.u >> 16) & 1u);
  return (ushort)(r >> 16);
}
__device__ __forceinline__ float bf2f(ushort h){
  union { unsigned u; float f; } v; v.u = ((unsigned)h) << 16; return v.f;
}
__device__ __forceinline__ float elu_f(float x){
  return x > 0.f ? x : expm1f(x);
}

// ---- unified prep: activations ----
struct AJob { const float* X; ushort* A; int total, K; };
__global__ void prep_act_all(AJob j0, AJob j1, int t0){
  int i = blockIdx.x * 256 + threadIdx.x;
  AJob J; int idx;
  if (i < t0){ J = j0; idx = i; }
  else { J = j1; idx = i - t0; if (idx >= J.total) return; }
  int row = idx / J.K, k = idx - row * J.K;
  float x = J.X[idx];
  ushort hi = f2bf(x);
  ushort lo = f2bf(x - bf2f(hi));
  size_t base = (size_t)row * (size_t)(2 * J.K);
  J.A[base + k] = hi;
  J.A[base + J.K + k] = lo;
}

// ---- unified prep: weights f32 [E][K][N] -> [E][N][2K] bf16 hi|lo ----
struct WJob { const float* W; ushort* Bt; int K, N, nb, nk, blkStart; };
struct WJobs { WJob j[6]; int njobs; };
__global__ void prep_w_all(WJobs jobs){
  __shared__ float tile[32][33];
  int b = blockIdx.x;
  int ji = 0;
  while (ji + 1 < jobs.njobs && b >= jobs.j[ji + 1].blkStart) ji++;
  WJob J = jobs.j[ji];
  int rem = b - J.blkStart;
  int x = rem % J.nb; rem /= J.nb;
  int y = rem % J.nk; int e = rem / J.nk;
  const float* w = J.W + (size_t)e * J.K * J.N;
  ushort* bt = J.Bt + (size_t)e * J.N * 2 * J.K;
  int n0 = x * 32, k0 = y * 32;
  for (int i = threadIdx.y; i < 32; i += 8)
    tile[i][threadIdx.x] = w[(size_t)(k0 + i) * J.N + n0 + threadIdx.x];
  __syncthreads();
  for (int jj = threadIdx.y; jj < 32; jj += 8){
    float v = tile[threadIdx.x][jj];
    ushort hi = f2bf(v);
    ushort lo = f2bf(v - bf2f(hi));
    size_t base = (size_t)(n0 + jj) * (size_t)(2 * J.K);
    bt[base + k0 + threadIdx.x] = hi;
    bt[base + J.K + k0 + threadIdx.x] = lo;
  }
}

// ---- descriptor-batched 256x256 GEMM, 4 phases/K-tile, deep staging ----
// mode 0: C = split bf16 [M][2N]; mode 1: C = f32 [M][N];
// mode 2: no C — ret[row*8+eidx] = sum_col elu(acc+bias)*w3[col] + rbp[0]
struct Slice {
  const ushort* A; const ushort* Bt; const float* bias; void* C;
  const float* w3; const float* rbp; float* ret;
  int N, K, log2gx, mode, blkStart, eidx;
};
struct SliceArr { Slice s[9]; int nz; };

__global__ __launch_bounds__(512, 2) void gemm8p(SliceArr args){
  __shared__ __align__(16) ushort As[2][256][64];   // 64KB
  __shared__ __align__(16) ushort Bs[2][256][64];   // 64KB
  __shared__ float red[4][256];                     // 4KB (mode-2 reduce)

  // XCD-chunked bijective swizzle (grids here are multiples of 8)
  const int nwg  = gridDim.x;
  const int orig = blockIdx.x;
  const int wg   = (orig & 7) * (nwg >> 3) + (orig >> 3);

  int z = 0;
  while (z + 1 < args.nz && wg >= args.s[z + 1].blkStart) z++;
  const Slice sl = args.s[z];
  const int rem = wg - sl.blkStart;
  const int gxm = (1 << sl.log2gx) - 1;
  const int bx  = rem & gxm;
  const int by  = rem >> sl.log2gx;

  const ushort* __restrict__ Ag = sl.A;
  const ushort* __restrict__ Bg = sl.Bt;
  const int K = sl.K;

  const int tid  = threadIdx.x;
  const int lane = tid & 63;
  const int wave = tid >> 6;
  const int wr = wave >> 2;                     // 0..1 (M sub-block within half)
  const int wc = wave & 3;                      // 0..3 (N sub-block within half)
  const int rowBase = by * 256;
  const int colBase = bx * 256;
  const int KB = K >> 6;
  const int NT = 3 * KB;
  const int lr = lane & 15;
  const int lk = (lane >> 4) << 3;
  const int swzR = (lr & 7) << 3;
  const size_t strideK2 = (size_t)(2 * K);

  const int rowS = tid >> 3;
  const int swzS = ((tid >> 3) & 7) << 3;
  const int colS = ((tid & 7) << 3) ^ swzS;

  // hx: 0=B half0, 1=B half1, 2=A half0, 3=A half1  (half h = rows h*128..h*128+127)
  auto stageHalf = [&](int t, int hx, int buf){
    int tt = (t < NT) ? t : (NT - 1);           // clamp: dead-but-safe
    int sec = (tt >= 2 * KB) ? 2 : (tt >= KB) ? 1 : 0;
    int inner = tt - sec * KB;
    bool isB = hx < 2;
    int h = hx & 1;
    int ko = (isB ? ((sec == 2) ? K : 0) : ((sec == 1) ? K : 0)) + (inner << 6);
    const ushort* gbase = isB ? Bg : Ag;
    int rb = (isB ? colBase : rowBase) + h * 128;
    char* lb = (char*)(isB ? &Bs[buf][0][0] : &As[buf][0][0]) + h * 16384;
    #pragma unroll
    for (int j = 0; j < 2; j++){
      const ushort* src = gbase + (size_t)(rb + j * 64 + rowS) * strideK2 + ko + colS;
      __builtin_amdgcn_global_load_lds((const AS1 void*)src,
                                       (AS3 void*)(lb + j * 8192 + tid * 16), 16, 0, 0);
    }
  };

  bf16x8 a[8], b[8];
  // read-half h == stage-half h: rows h*128 + wr*64 + m*16 + lr
  auto loadA = [&](int buf, int h){
    #pragma unroll
    for (int m = 0; m < 4; m++)
      #pragma unroll
      for (int ks = 0; ks < 2; ks++)
        a[m * 2 + ks] = *(const bf16x8*)&As[buf][h * 128 + wr * 64 + m * 16 + lr][(ks * 32 + lk) ^ swzR];
  };
  // rows h*128 + wc*32 + n2*16 + lr
  auto loadB = [&](int buf, int h){
    #pragma unroll
    for (int n2 = 0; n2 < 2; n2++)
      #pragma unroll
      for (int ks = 0; ks < 2; ks++)
        b[h * 4 + n2 * 2 + ks] = *(const bf16x8*)&Bs[buf][h * 128 + wc * 32 + n2 * 16 + lr][(ks * 32 + lk) ^ swzR];
  };

  f32x4 acc[8][4];
  #pragma unroll
  for (int m = 0; m < 8; m++)
    #pragma unroll
    for (int n = 0; n < 4; n++)
      acc[m][n] = (f32x4){0.f, 0.f, 0.f, 0.f};

  // acc[mh*4+m][nh*2+n] = output rows mh*128+wr*64+m*16.., cols nh*128+wc*32+n*16..
  auto mfmaQ = [&](int mh, int nh){
    #pragma unroll
    for (int m = 0; m < 4; m++)
      #pragma unroll
      for (int n = 0; n < 2; n++)
        #pragma unroll
        for (int ks = 0; ks < 2; ks++)
          acc[mh * 4 + m][nh * 2 + n] = __builtin_amdgcn_mfma_f32_16x16x32_bf16(
              a[m * 2 + ks], b[nh * 4 + n * 2 + ks], acc[mh * 4 + m][nh * 2 + n], 0, 0, 0);
  };

  // prologue: tile0 -> buf0, tile1 -> buf1 (16 loads); wait tile0 only
  #pragma unroll
  for (int hx = 0; hx < 4; hx++) stageHalf(0, hx, 0);
  #pragma unroll
  for (int hx = 0; hx < 4; hx++) stageHalf(1, hx, 1);
  asm volatile("s_waitcnt vmcnt(8)" ::: "memory");
  SCHED0; SBAR; SCHED0;

  for (int t = 0; t < NT; ++t){
    const int cur = t & 1;
    // ph0: read A0+B0 (rows 0-127) | MFMA q(0,0)
    loadA(cur, 0); loadB(cur, 0);
    SCHED0; SBAR;
    asm volatile("s_waitcnt lgkmcnt(0)" ::: "memory"); SCHED0;
    __builtin_amdgcn_s_setprio(1); mfmaQ(0, 0); __builtin_amdgcn_s_setprio(0);
    SCHED0; SBAR; SCHED0;
    // ph1: read B1 (rows 128-255) | stage t+2.A0 -> cur (rows 0-127, read done ph0) | MFMA q(0,1)
    loadB(cur, 1);
    stageHalf(t + 2, 2, cur);
    SCHED0; SBAR;
    asm volatile("s_waitcnt lgkmcnt(0)" ::: "memory"); SCHED0;
    __builtin_amdgcn_s_setprio(1); mfmaQ(0, 1); __builtin_amdgcn_s_setprio(0);
    SCHED0; SBAR; SCHED0;
    // ph2: read A1 (rows 128-255) | stage t+2.B0 -> cur (rows 0-127, read done ph0) | MFMA q(1,1)
    loadA(cur, 1);
    stageHalf(t + 2, 0, cur);
    SCHED0; SBAR;
    asm volatile("s_waitcnt lgkmcnt(0)" ::: "memory"); SCHED0;
    __builtin_amdgcn_s_setprio(1); mfmaQ(1, 1); __builtin_amdgcn_s_setprio(0);
    SCHED0; SBAR; SCHED0;
    // ph3: stage t+2.{B1,A1} -> cur (rows 128-255, reads done ph1/ph2) | MFMA q(1,0) | vmcnt(8) drains t+1
    stageHalf(t + 2, 1, cur);
    stageHalf(t + 2, 3, cur);
    SCHED0;
    __builtin_amdgcn_s_setprio(1); mfmaQ(1, 0); __builtin_amdgcn_s_setprio(0);
    SCHED0;
    asm volatile("s_waitcnt vmcnt(8)" ::: "memory");
    SBAR; SCHED0;
  }

  // ---- epilogue ----
  // acc[m8][n]: row = rowBase + (m8>>2)*128 + wr*64 + (m8&3)*16 + (lane>>4)*4 + r
  //             col = colBase + (n>>1)*128 + wc*32 + (n&1)*16 + lr
  const int rsub = wr * 64 + ((lane >> 4) << 2);

  if (sl.mode == 2){
    // fused final expert layer: ret[row] = sum_col elu(h2)*w3[col] + b3
    __syncthreads();
    #pragma unroll
    for (int m = 0; m < 8; m++){
      float p4[4] = {0.f, 0.f, 0.f, 0.f};
      #pragma unroll
      for (int n = 0; n < 4; n++){
        int col = colBase + ((n >> 1) << 7) + wc * 32 + ((n & 1) << 4) + lr;
        float bv = sl.bias[col];
        float wv = sl.w3[col];
        #pragma unroll
        for (int r = 0; r < 4; r++)
          p4[r] += elu_f(acc[m][n][r] + bv) * wv;
      }
      #pragma unroll
      for (int r = 0; r < 4; r++){
        #pragma unroll
        for (int s = 8; s > 0; s >>= 1) p4[r] += __shfl_xor(p4[r], s, 64);
      }
      if ((lane & 15) == 0){
        int hig = lane >> 4;
        int rowoff = ((m >> 2) << 7) + wr * 64 + ((m & 3) << 4) + hig * 4;
        #pragma unroll
        for (int r = 0; r < 4; r++)
          red[wc][rowoff + r] = p4[r];
      }
    }
    __syncthreads();
    if (tid < 256){
      float s4 = red[0][tid] + red[1][tid] + red[2][tid] + red[3][tid];
      sl.ret[(size_t)(rowBase + tid) * 8 + sl.eidx] = s4 + sl.rbp[0];
    }
    return;
  }

  const int N = sl.N;
  #pragma unroll
  for (int m = 0; m < 8; m++){
    int row0 = rowBase + ((m >> 2) << 7) + rsub + ((m & 3) << 4);
    #pragma unroll
    for (int n = 0; n < 4; n++){
      int col = colBase + ((n >> 1) << 7) + wc * 32 + ((n & 1) << 4) + lr;
      float bv = sl.bias[col];
      #pragma unroll
      for (int r = 0; r < 4; r++){
        int row = row0 + r;
        float v = elu_f(acc[m][n][r] + bv);
        if (sl.mode == 0){
          ushort hi = f2bf(v);
          ushort lo = f2bf(v - bf2f(hi));
          ushort* C = (ushort*)sl.C;
          size_t base = (size_t)row * (size_t)(2 * N);
          C[base + col] = hi;
          C[base + N + col] = lo;
        } else {
          ((float*)sl.C)[(size_t)row * N + col] = v;
        }
      }
    }
  }
}

// ---- gate final layer + softmax ----
__global__ void gate3_softmax(const float* __restrict__ g2, const float* __restrict__ gw3,
                              const float* __restrict__ gb3, float* __restrict__ wts){
  int row = blockIdx.x * 4 + (threadIdx.x >> 6);
  int lane = threadIdx.x & 63;
  const float* g = g2 + (size_t)row * 256;
  float p[8];
  #pragma unroll
  for (int j = 0; j < 8; j++) p[j] = 0.f;
  for (int k = lane; k < 256; k += 64){
    float x = g[k];
    #pragma unroll
    for (int j = 0; j < 8; j++) p[j] += x * gw3[k * 8 + j];
  }
  #pragma unroll
  for (int j = 0; j < 8; j++){
    #pragma unroll
    for (int s = 32; s > 0; s >>= 1) p[j] += __shfl_xor(p[j], s, 64);
  }
  float mx = -1e30f;
  #pragma unroll
  for (int j = 0; j < 8; j++){ p[j] += gb3[j]; mx = fmaxf(mx, p[j]); }
  float sum = 0.f;
  #pragma unroll
  for (int j = 0; j < 8; j++){ p[j] = expf(p[j] - mx); sum += p[j]; }
  float inv = 1.f / sum;
  #pragma unroll
  for (int j = 0; j < 8; j++)
    if (lane == j) wts[(size_t)row * 8 + j] = p[j] * inv;
}

// ---- final combine ----
__global__ void combine(const float* __restrict__ wts, const float* __restrict__ ret,
                        float* __restrict__ out){
  int i = blockIdx.x * blockDim.x + threadIdx.x;
  if (i >= 8192) return;
  float s = 0.f;
  #pragma unroll
  for (int j = 0; j < 8; j++) s += wts[(size_t)i * 8 + j] * ret[(size_t)i * 8 + j];
  out[i] = s;
}

extern "C" void kernel_launch(void* const* d_in, const int* in_sizes, int n_in,
                              void* d_out, int out_size, void* d_ws, size_t ws_size,
                              hipStream_t stream){
  const float* obs  = (const float*)d_in[0];
  const float* code = (const float*)d_in[1];
  const float* ew0  = (const float*)d_in[2];
  const float* eb0  = (const float*)d_in[3];
  const float* ew1  = (const float*)d_in[4];
  const float* eb1  = (const float*)d_in[5];
  const float* ew2  = (const float*)d_in[6];
  const float* eb2  = (const float*)d_in[7];
  const float* ew3  = (const float*)d_in[8];
  const float* eb3  = (const float*)d_in[9];
  const float* gw0  = (const float*)d_in[10];
  const float* gb0  = (const float*)d_in[11];
  const float* gw1  = (const float*)d_in[12];
  const float* gb1  = (const float*)d_in[13];
  const float* gw2  = (const float*)d_in[14];
  const float* gb2  = (const float*)d_in[15];
  const float* gw3  = (const float*)d_in[16];
  const float* gb3  = (const float*)d_in[17];
  (void)in_sizes; (void)n_in; (void)out_size;

  char* ws = (char*)d_ws;
  size_t off = 0;
  auto alloc = [&](size_t bytes) -> void* {
    void* p = ws + off;
    off += (bytes + 255) & ~(size_t)255;
    return p;
  };
  ushort* A_obs  = (ushort*)alloc(8192ull * 1024 * 2);
  ushort* A_code = (ushort*)alloc(8192ull * 128 * 2);
  ushort* B_ew0  = (ushort*)alloc(8ull * 1024 * 1024 * 2);
  ushort* B_ew1  = (ushort*)alloc(8ull * 512 * 2048 * 2);
  ushort* B_ew2  = (ushort*)alloc(8ull * 256 * 1024 * 2);
  ushort* B_gw0  = (ushort*)alloc(1024ull * 128 * 2);
  ushort* B_gw1  = (ushort*)alloc(512ull * 2048 * 2);
  ushort* B_gw2  = (ushort*)alloc(256ull * 1024 * 2);
  float*  wts    = (float*)alloc(8192ull * 8 * 4);
  float*  ret    = (float*)alloc(8192ull * 8 * 4);
  const size_t fixed = off;

  const size_t sl0b = 8192ull * 2048 * 2;   // h0 split bf16 (32MiB)
  const size_t sl1b = 8192ull * 1024 * 2;   // h1 split bf16 (16MiB)
  const size_t pairB = sl0b + sl1b;

  int G = 0;
  {
    const int cand[5] = {8, 4, 3, 2, 1};
    for (int ci = 0; ci < 5; ci++)
      if (fixed + (size_t)(cand[ci] + 1) * pairB <= ws_size){ G = cand[ci]; break; }
  }
  const bool gateFirst = (G == 0);
  const int ns = gateFirst ? 1 : (G + 1);
  ushort* h0buf = (ushort*)alloc((size_t)ns * sl0b);
  ushort* h1buf = (ushort*)alloc((size_t)ns * sl1b);
  const size_t sl0e = 8192ull * 2048;
  const size_t sl1e = 8192ull * 1024;
  const int gsl = ns - 1;
  ushort* h0g = h0buf + (size_t)gsl * sl0e;
  ushort* h1g = h1buf + (size_t)gsl * sl1e;
  float*  h2g = (float*)h0g;                 // alias: h0g dead after gate L1

  // prep (2 dispatches)
  {
    AJob j0 = {obs,  A_obs,  8192 * 512, 512};
    AJob j1 = {code, A_code, 8192 * 64,  64};
    int t0 = 8192 * 512;
    prep_act_all<<<dim3((t0 + j1.total + 255) / 256), 256, 0, stream>>>(j0, j1, t0);

    WJobs wj; wj.njobs = 6;
    int bs = 0;
    auto addW = [&](int i, const float* W, ushort* Bt, int K, int N, int E){
      wj.j[i] = {W, Bt, K, N, N / 32, K / 32, bs};
      bs += E * (N / 32) * (K / 32);
    };
    addW(0, ew0, B_ew0, 512, 1024, 8);
    addW(1, ew1, B_ew1, 1024, 512, 8);
    addW(2, ew2, B_ew2, 512, 256, 8);
    addW(3, gw0, B_gw0, 64, 1024, 1);
    addW(4, gw1, B_gw1, 1024, 512, 1);
    addW(5, gw2, B_gw2, 512, 256, 1);
    prep_w_all<<<dim3(bs), dim3(32, 8), 0, stream>>>(wj);
  }

  auto runGroup = [&](int e0, int cnt, bool withGate){
    SliceArr sa; int nb;
    // L0
    nb = 0; sa.nz = cnt + (withGate ? 1 : 0);
    for (int i = 0; i < cnt; i++){ int e = e0 + i;
      sa.s[i] = {A_obs, B_ew0 + (size_t)e * 1024 * 1024, eb0 + e * 1024,
                 h0buf + (size_t)i * sl0e, nullptr, nullptr, nullptr,
                 1024, 512, 2, 0, nb, 0};
      nb += 4 * 32;
    }
    if (withGate){
      sa.s[cnt] = {A_code, B_gw0, gb0, h0g, nullptr, nullptr, nullptr,
                   1024, 64, 2, 0, nb, 0};
      nb += 4 * 32;
    }
    for (int i = sa.nz; i < 9; i++) sa.s[i] = sa.s[0];
    gemm8p<<<dim3(nb), 512, 0, stream>>>(sa);
    // L1
    nb = 0;
    for (int i = 0; i < cnt; i++){ int e = e0 + i;
      sa.s[i] = {h0buf + (size_t)i * sl0e, B_ew1 + (size_t)e * 512 * 2048, eb1 + e * 512,
                 h1buf + (size_t)i * sl1e, nullptr, nullptr, nullptr,
                 512, 1024, 1, 0, nb, 0};
      nb += 2 * 32;
    }
    if (withGate){
      sa.s[cnt] = {h0g, B_gw1, gb1, h1g, nullptr, nullptr, nullptr,
                   512, 1024, 1, 0, nb, 0};
      nb += 2 * 32;
    }
    gemm8p<<<dim3(nb), 512, 0, stream>>>(sa);
    // L2: experts fused-returns (mode 2); gate f32 h2 (mode 1)
    nb = 0;
    for (int i = 0; i < cnt; i++){ int e = e0 + i;
      sa.s[i] = {h1buf + (size_t)i * sl1e, B_ew2 + (size_t)e * 256 * 1024, eb2 + e * 256,
                 nullptr, ew3 + (size_t)e * 256, eb3 + e, ret,
                 256, 512, 0, 2, nb, e};
      nb += 32;
    }
    if (withGate){
      sa.s[cnt] = {h1g, B_gw2, gb2, h2g, nullptr, nullptr, nullptr,
                   256, 512, 0, 1, nb, 0};
      nb += 32;
    }
    gemm8p<<<dim3(nb), 512, 0, stream>>>(sa);
    if (withGate)
      gate3_softmax<<<dim3(2048), 256, 0, stream>>>(h2g, gw3, gb3, wts);
  };

  if (gateFirst){
    SliceArr sa; sa.nz = 1;
    sa.s[0] = {A_code, B_gw0, gb0, h0g, nullptr, nullptr, nullptr, 1024, 64, 2, 0, 0, 0};
    for (int i = 1; i < 9; i++) sa.s[i] = sa.s[0];
    gemm8p<<<dim3(128), 512, 0, stream>>>(sa);
    sa.s[0] = {h0g, B_gw1, gb1, h1g, nullptr, nullptr, nullptr, 512, 1024, 1, 0, 0, 0};
    gemm8p<<<dim3(64), 512, 0, stream>>>(sa);
    sa.s[0] = {h1g, B_gw2, gb2, h2g, nullptr, nullptr, nullptr, 256, 512, 0, 1, 0, 0};
    gemm8p<<<dim3(32), 512, 0, stream>>>(sa);
    gate3_softmax<<<dim3(2048), 256, 0, stream>>>(h2g, gw3, gb3, wts);
    for (int e = 0; e < 8; e++) runGroup(e, 1, false);
  } else {
    bool first = true;
    for (int e0 = 0; e0 < 8; ){
      int cnt = (8 - e0 < G) ? (8 - e0) : G;
      runGroup(e0, cnt, first);
      first = false;
      e0 += cnt;
    }
  }

  combine<<<dim3(8192 / 256), 256, 0, stream>>>(wts, ret, (float*)d_out);
}

// Round 8
// 738.033 us; speedup vs baseline: 1.6659x; 1.3335x over previous
//
#include <hip/hip_runtime.h>
#include <hip/hip_bf16.h>
#include <math.h>

// B=8192, D=512, V=64, E=8, hidden (1024,512,256)
// All matmuls as bf16 MFMA with hi/lo split (3 products):
//   C = Ahi*Bhi + Alo*Bhi + Ahi*Blo.  A: [M][2K] hi|lo, Bt: [N][2K] hi|lo.
// Round 8: fused 4-operand staging — loop over REAL K-tiles, stage
// {Ahi,Alo,Bhi,Blo} once (128KB single-set LDS), compute the 3 section
// products as 3 phases (S1: Alo*Bhi, S0: Ahi*Bhi [b reused], S2: Ahi*Blo).
// 3 barriers/K-step (was 8), linear staging addresses, counted vmcnt,
// cvt_pk+__expf epilogue. Host/launch identical to R7.

typedef short bf16x8 __attribute__((ext_vector_type(8)));
typedef float f32x4 __attribute__((ext_vector_type(4)));

#define AS1 __attribute__((address_space(1)))
#define AS3 __attribute__((address_space(3)))
#define SCHED0 __builtin_amdgcn_sched_barrier(0)
#define SBAR __builtin_amdgcn_s_barrier()

__device__ __forceinline__ ushort f2bf(float x){
  union { float f; unsigned u; } v; v.f = x;
  unsigned r = v.u + 0x7fffu + ((v.u >> 16) & 1u);
  return (ushort)(r >> 16);
}
__device__ __forceinline__ float bf2f(ushort h){
  union { unsigned u; float f; } v; v.u = ((unsigned)h) << 16; return v.f;
}
__device__ __forceinline__ float elu_f(float x){
  return x > 0.f ? x : __expf(x) - 1.f;
}

// ---- unified prep: activations ----
struct AJob { const float* X; ushort* A; int total, K; };
__global__ void prep_act_all(AJob j0, AJob j1, int t0){
  int i = blockIdx.x * 256 + threadIdx.x;
  AJob J; int idx;
  if (i < t0){ J = j0; idx = i; }
  else { J = j1; idx = i - t0; if (idx >= J.total) return; }
  int row = idx / J.K, k = idx - row * J.K;
  float x = J.X[idx];
  ushort hi = f2bf(x);
  ushort lo = f2bf(x - bf2f(hi));
  size_t base = (size_t)row * (size_t)(2 * J.K);
  J.A[base + k] = hi;
  J.A[base + J.K + k] = lo;
}

// ---- unified prep: weights f32 [E][K][N] -> [E][N][2K] bf16 hi|lo ----
struct WJob { const float* W; ushort* Bt; int K, N, nb, nk, blkStart; };
struct WJobs { WJob j[6]; int njobs; };
__global__ void prep_w_all(WJobs jobs){
  __shared__ float tile[32][33];
  int b = blockIdx.x;
  int ji = 0;
  while (ji + 1 < jobs.njobs && b >= jobs.j[ji + 1].blkStart) ji++;
  WJob J = jobs.j[ji];
  int rem = b - J.blkStart;
  int x = rem % J.nb; rem /= J.nb;
  int y = rem % J.nk; int e = rem / J.nk;
  const float* w = J.W + (size_t)e * J.K * J.N;
  ushort* bt = J.Bt + (size_t)e * J.N * 2 * J.K;
  int n0 = x * 32, k0 = y * 32;
  for (int i = threadIdx.y; i < 32; i += 8)
    tile[i][threadIdx.x] = w[(size_t)(k0 + i) * J.N + n0 + threadIdx.x];
  __syncthreads();
  for (int jj = threadIdx.y; jj < 32; jj += 8){
    float v = tile[threadIdx.x][jj];
    ushort hi = f2bf(v);
    ushort lo = f2bf(v - bf2f(hi));
    size_t base = (size_t)(n0 + jj) * (size_t)(2 * J.K);
    bt[base + k0 + threadIdx.x] = hi;
    bt[base + J.K + k0 + threadIdx.x] = lo;
  }
}

// ---- descriptor-batched 256x256 GEMM, fused 4-operand K-loop ----
// mode 0: C = split bf16 [M][2N]; mode 1: C = f32 [M][N];
// mode 2: no C — ret[row*8+eidx] = sum_col elu(acc+bias)*w3[col] + rbp[0]
struct Slice {
  const ushort* A; const ushort* Bt; const float* bias; void* C;
  const float* w3; const float* rbp; float* ret;
  int N, K, log2gx, mode, blkStart, eidx;
};
struct SliceArr { Slice s[9]; int nz; };

__global__ __launch_bounds__(512, 2) void gemm8p(SliceArr args){
  // operand tiles: 0=Ahi, 1=Alo, 2=Bhi, 3=Blo  (each 256x64 bf16 = 32KB)
  __shared__ __align__(16) ushort lds[4][256][64];  // 128KB
  __shared__ float red[4][256];                     // 4KB (mode-2 reduce)

  // XCD-chunked bijective swizzle (grids here are multiples of 8)
  const int nwg  = gridDim.x;
  const int orig = blockIdx.x;
  const int wg   = (orig & 7) * (nwg >> 3) + (orig >> 3);

  int z = 0;
  while (z + 1 < args.nz && wg >= args.s[z + 1].blkStart) z++;
  const Slice sl = args.s[z];
  const int rem = wg - sl.blkStart;
  const int gxm = (1 << sl.log2gx) - 1;
  const int bx  = rem & gxm;
  const int by  = rem >> sl.log2gx;

  const ushort* __restrict__ Ag = sl.A;
  const ushort* __restrict__ Bg = sl.Bt;
  const int K = sl.K;

  const int tid  = threadIdx.x;
  const int lane = tid & 63;
  const int wave = tid >> 6;
  const int wr = wave >> 2;                     // 0..1 : rows wr*128..+127
  const int wc = wave & 3;                      // 0..3 : cols wc*64..+63
  const int rowBase = by * 256;
  const int colBase = bx * 256;
  const int KB = K >> 6;                        // real-K tiles
  const int lr = lane & 15;
  const int lk = (lane >> 4) << 3;
  const int swzR = (lr & 7) << 3;
  const size_t strideK2 = (size_t)(2 * K);

  const int rowS = tid >> 3;                    // 0..63
  const int swzS = ((tid >> 3) & 7) << 3;
  const int colS = ((tid & 7) << 3) ^ swzS;

  // stage operand tile op for real-K step t (4 load-instrs, linear col adv)
  auto stage = [&](int op, int t){
    int tt = (t < KB) ? t : (KB - 1);           // clamp: dead-but-safe
    bool isA = op < 2;
    const ushort* gb = isA ? Ag : Bg;
    int rb = isA ? rowBase : colBase;
    int kc = ((op & 1) ? K : 0) + (tt << 6) + colS;
    char* lb = (char*)&lds[op][0][0];
    #pragma unroll
    for (int j = 0; j < 4; j++){
      const ushort* src = gb + (size_t)(rb + j * 64 + rowS) * strideK2 + kc;
      __builtin_amdgcn_global_load_lds((const AS1 void*)src,
                                       (AS3 void*)(lb + j * 8192 + tid * 16), 16, 0, 0);
    }
  };

  bf16x8 a[8], b[8];
  auto readB = [&](int op){
    #pragma unroll
    for (int n = 0; n < 4; n++)
      #pragma unroll
      for (int ks = 0; ks < 2; ks++)
        b[n * 2 + ks] = *(const bf16x8*)&lds[op][wc * 64 + n * 16 + lr][(ks * 32 + lk) ^ swzR];
  };
  auto readAh = [&](int op, int mh){            // half mh: rows wr*128+mh*64..
    #pragma unroll
    for (int m = 0; m < 4; m++)
      #pragma unroll
      for (int ks = 0; ks < 2; ks++)
        a[m * 2 + ks] = *(const bf16x8*)&lds[op][wr * 128 + mh * 64 + m * 16 + lr][(ks * 32 + lk) ^ swzR];
  };

  f32x4 acc[8][4];
  #pragma unroll
  for (int m = 0; m < 8; m++)
    #pragma unroll
    for (int n = 0; n < 4; n++)
      acc[m][n] = (f32x4){0.f, 0.f, 0.f, 0.f};

  auto mfmaH = [&](int mh){
    #pragma unroll
    for (int m = 0; m < 4; m++)
      #pragma unroll
      for (int n = 0; n < 4; n++)
        #pragma unroll
        for (int ks = 0; ks < 2; ks++)
          acc[mh * 4 + m][n] = __builtin_amdgcn_mfma_f32_16x16x32_bf16(
              a[m * 2 + ks], b[n * 2 + ks], acc[mh * 4 + m][n], 0, 0, 0);
  };

  // prologue: Alo(0), Bhi(0)
  stage(1, 0); stage(2, 0);
  asm volatile("s_waitcnt vmcnt(0)" ::: "memory");
  SCHED0; SBAR; SCHED0;

  for (int t = 0; t < KB; ++t){
    // ---- ph1: S1 = Alo x Bhi | stage Ahi(t), Blo(t)
    stage(0, t); stage(3, t);
    readB(2);
    readAh(1, 0);
    asm volatile("s_waitcnt lgkmcnt(0)" ::: "memory"); SCHED0;
    __builtin_amdgcn_s_setprio(1); mfmaH(0); __builtin_amdgcn_s_setprio(0);
    readAh(1, 1);
    asm volatile("s_waitcnt lgkmcnt(0)" ::: "memory"); SCHED0;
    __builtin_amdgcn_s_setprio(1); mfmaH(1); __builtin_amdgcn_s_setprio(0);
    SCHED0;
    asm volatile("s_waitcnt vmcnt(4)" ::: "memory");  // Ahi(t) landed
    SBAR; SCHED0;
    // ---- ph2: S0 = Ahi x Bhi (b reused) | stage Alo(t+1), Bhi(t+1)
    stage(1, t + 1); stage(2, t + 1);
    readAh(0, 0);
    asm volatile("s_waitcnt lgkmcnt(0)" ::: "memory"); SCHED0;
    __builtin_amdgcn_s_setprio(1); mfmaH(0); __builtin_amdgcn_s_setprio(0);
    readAh(0, 1);
    asm volatile("s_waitcnt lgkmcnt(0)" ::: "memory"); SCHED0;
    __builtin_amdgcn_s_setprio(1); mfmaH(1); __builtin_amdgcn_s_setprio(0);
    SCHED0;
    asm volatile("s_waitcnt vmcnt(8)" ::: "memory");  // Blo(t) landed
    SBAR; SCHED0;
    // ---- ph3: S2 = Ahi x Blo | no stages
    readB(3);
    readAh(0, 0);
    asm volatile("s_waitcnt lgkmcnt(0)" ::: "memory"); SCHED0;
    __builtin_amdgcn_s_setprio(1); mfmaH(0); __builtin_amdgcn_s_setprio(0);
    readAh(0, 1);
    asm volatile("s_waitcnt lgkmcnt(0)" ::: "memory"); SCHED0;
    __builtin_amdgcn_s_setprio(1); mfmaH(1); __builtin_amdgcn_s_setprio(0);
    SCHED0;
    asm volatile("s_waitcnt vmcnt(0)" ::: "memory");  // Alo/Bhi(t+1) landed
    SBAR; SCHED0;
  }

  // ---- epilogue ----
  // acc[m8][n]: row = rowBase + wr*128 + (m8>>2)*64 + (m8&3)*16 + (lane>>4)*4 + r
  //             col = colBase + wc*64 + n*16 + lr
  if (sl.mode == 2){
    __syncthreads();
    #pragma unroll
    for (int m = 0; m < 8; m++){
      float p4[4] = {0.f, 0.f, 0.f, 0.f};
      #pragma unroll
      for (int n = 0; n < 4; n++){
        int col = colBase + wc * 64 + n * 16 + lr;
        float bv = sl.bias[col];
        float wv = sl.w3[col];
        #pragma unroll
        for (int r = 0; r < 4; r++)
          p4[r] += elu_f(acc[m][n][r] + bv) * wv;
      }
      #pragma unroll
      for (int r = 0; r < 4; r++){
        #pragma unroll
        for (int s = 8; s > 0; s >>= 1) p4[r] += __shfl_xor(p4[r], s, 64);
      }
      if ((lane & 15) == 0){
        int hig = lane >> 4;
        int rowoff = wr * 128 + ((m >> 2) << 6) + ((m & 3) << 4) + hig * 4;
        #pragma unroll
        for (int r = 0; r < 4; r++)
          red[wc][rowoff + r] = p4[r];
      }
    }
    __syncthreads();
    if (tid < 256){
      float s4 = red[0][tid] + red[1][tid] + red[2][tid] + red[3][tid];
      sl.ret[(size_t)(rowBase + tid) * 8 + sl.eidx] = s4 + sl.rbp[0];
    }
    return;
  }

  const int N = sl.N;
  #pragma unroll
  for (int m = 0; m < 8; m++){
    int row0 = rowBase + wr * 128 + ((m >> 2) << 6) + ((m & 3) << 4) + ((lane >> 4) << 2);
    #pragma unroll
    for (int n = 0; n < 4; n++){
      int col = colBase + wc * 64 + n * 16 + lr;
      float bv = sl.bias[col];
      float v0 = elu_f(acc[m][n][0] + bv);
      float v1 = elu_f(acc[m][n][1] + bv);
      float v2 = elu_f(acc[m][n][2] + bv);
      float v3 = elu_f(acc[m][n][3] + bv);
      if (sl.mode == 0){
        unsigned ph01, ph23, pl01, pl23;
        asm("v_cvt_pk_bf16_f32 %0, %1, %2" : "=v"(ph01) : "v"(v0), "v"(v1));
        asm("v_cvt_pk_bf16_f32 %0, %1, %2" : "=v"(ph23) : "v"(v2), "v"(v3));
        union { unsigned u; float f; } c0, c1, c2, c3;
        c0.u = ph01 << 16; c1.u = ph01 & 0xffff0000u;
        c2.u = ph23 << 16; c3.u = ph23 & 0xffff0000u;
        asm("v_cvt_pk_bf16_f32 %0, %1, %2" : "=v"(pl01) : "v"(v0 - c0.f), "v"(v1 - c1.f));
        asm("v_cvt_pk_bf16_f32 %0, %1, %2" : "=v"(pl23) : "v"(v2 - c2.f), "v"(v3 - c3.f));
        ushort* C = (ushort*)sl.C;
        size_t s2n = (size_t)(2 * N);
        size_t r0b = (size_t)row0 * s2n + col;
        C[r0b]            = (ushort)ph01;
        C[r0b + s2n]      = (ushort)(ph01 >> 16);
        C[r0b + 2 * s2n]  = (ushort)ph23;
        C[r0b + 3 * s2n]  = (ushort)(ph23 >> 16);
        size_t r0l = r0b + N;
        C[r0l]            = (ushort)pl01;
        C[r0l + s2n]      = (ushort)(pl01 >> 16);
        C[r0l + 2 * s2n]  = (ushort)pl23;
        C[r0l + 3 * s2n]  = (ushort)(pl23 >> 16);
      } else {
        float* C = (float*)sl.C;
        size_t r0b = (size_t)row0 * N + col;
        C[r0b]         = v0;
        C[r0b + N]     = v1;
        C[r0b + 2 * N] = v2;
        C[r0b + 3 * N] = v3;
      }
    }
  }
}

// ---- gate final layer + softmax ----
__global__ void gate3_softmax(const float* __restrict__ g2, const float* __restrict__ gw3,
                              const float* __restrict__ gb3, float* __restrict__ wts){
  int row = blockIdx.x * 4 + (threadIdx.x >> 6);
  int lane = threadIdx.x & 63;
  const float* g = g2 + (size_t)row * 256;
  float p[8];
  #pragma unroll
  for (int j = 0; j < 8; j++) p[j] = 0.f;
  for (int k = lane; k < 256; k += 64){
    float x = g[k];
    #pragma unroll
    for (int j = 0; j < 8; j++) p[j] += x * gw3[k * 8 + j];
  }
  #pragma unroll
  for (int j = 0; j < 8; j++){
    #pragma unroll
    for (int s = 32; s > 0; s >>= 1) p[j] += __shfl_xor(p[j], s, 64);
  }
  float mx = -1e30f;
  #pragma unroll
  for (int j = 0; j < 8; j++){ p[j] += gb3[j]; mx = fmaxf(mx, p[j]); }
  float sum = 0.f;
  #pragma unroll
  for (int j = 0; j < 8; j++){ p[j] = expf(p[j] - mx); sum += p[j]; }
  float inv = 1.f / sum;
  #pragma unroll
  for (int j = 0; j < 8; j++)
    if (lane == j) wts[(size_t)row * 8 + j] = p[j] * inv;
}

// ---- final combine ----
__global__ void combine(const float* __restrict__ wts, const float* __restrict__ ret,
                        float* __restrict__ out){
  int i = blockIdx.x * blockDim.x + threadIdx.x;
  if (i >= 8192) return;
  float s = 0.f;
  #pragma unroll
  for (int j = 0; j < 8; j++) s += wts[(size_t)i * 8 + j] * ret[(size_t)i * 8 + j];
  out[i] = s;
}

extern "C" void kernel_launch(void* const* d_in, const int* in_sizes, int n_in,
                              void* d_out, int out_size, void* d_ws, size_t ws_size,
                              hipStream_t stream){
  const float* obs  = (const float*)d_in[0];
  const float* code = (const float*)d_in[1];
  const float* ew0  = (const float*)d_in[2];
  const float* eb0  = (const float*)d_in[3];
  const float* ew1  = (const float*)d_in[4];
  const float* eb1  = (const float*)d_in[5];
  const float* ew2  = (const float*)d_in[6];
  const float* eb2  = (const float*)d_in[7];
  const float* ew3  = (const float*)d_in[8];
  const float* eb3  = (const float*)d_in[9];
  const float* gw0  = (const float*)d_in[10];
  const float* gb0  = (const float*)d_in[11];
  const float* gw1  = (const float*)d_in[12];
  const float* gb1  = (const float*)d_in[13];
  const float* gw2  = (const float*)d_in[14];
  const float* gb2  = (const float*)d_in[15];
  const float* gw3  = (const float*)d_in[16];
  const float* gb3  = (const float*)d_in[17];
  (void)in_sizes; (void)n_in; (void)out_size;

  char* ws = (char*)d_ws;
  size_t off = 0;
  auto alloc = [&](size_t bytes) -> void* {
    void* p = ws + off;
    off += (bytes + 255) & ~(size_t)255;
    return p;
  };
  ushort* A_obs  = (ushort*)alloc(8192ull * 1024 * 2);
  ushort* A_code = (ushort*)alloc(8192ull * 128 * 2);
  ushort* B_ew0  = (ushort*)alloc(8ull * 1024 * 1024 * 2);
  ushort* B_ew1  = (ushort*)alloc(8ull * 512 * 2048 * 2);
  ushort* B_ew2  = (ushort*)alloc(8ull * 256 * 1024 * 2);
  ushort* B_gw0  = (ushort*)alloc(1024ull * 128 * 2);
  ushort* B_gw1  = (ushort*)alloc(512ull * 2048 * 2);
  ushort* B_gw2  = (ushort*)alloc(256ull * 1024 * 2);
  float*  wts    = (float*)alloc(8192ull * 8 * 4);
  float*  ret    = (float*)alloc(8192ull * 8 * 4);
  const size_t fixed = off;

  const size_t sl0b = 8192ull * 2048 * 2;   // h0 split bf16 (32MiB)
  const size_t sl1b = 8192ull * 1024 * 2;   // h1 split bf16 (16MiB)
  const size_t pairB = sl0b + sl1b;

  int G = 0;
  {
    const int cand[5] = {8, 4, 3, 2, 1};
    for (int ci = 0; ci < 5; ci++)
      if (fixed + (size_t)(cand[ci] + 1) * pairB <= ws_size){ G = cand[ci]; break; }
  }
  const bool gateFirst = (G == 0);
  const int ns = gateFirst ? 1 : (G + 1);
  ushort* h0buf = (ushort*)alloc((size_t)ns * sl0b);
  ushort* h1buf = (ushort*)alloc((size_t)ns * sl1b);
  const size_t sl0e = 8192ull * 2048;
  const size_t sl1e = 8192ull * 1024;
  const int gsl = ns - 1;
  ushort* h0g = h0buf + (size_t)gsl * sl0e;
  ushort* h1g = h1buf + (size_t)gsl * sl1e;
  float*  h2g = (float*)h0g;                 // alias: h0g dead after gate L1

  // prep (2 dispatches)
  {
    AJob j0 = {obs,  A_obs,  8192 * 512, 512};
    AJob j1 = {code, A_code, 8192 * 64,  64};
    int t0 = 8192 * 512;
    prep_act_all<<<dim3((t0 + j1.total + 255) / 256), 256, 0, stream>>>(j0, j1, t0);

    WJobs wj; wj.njobs = 6;
    int bs = 0;
    auto addW = [&](int i, const float* W, ushort* Bt, int K, int N, int E){
      wj.j[i] = {W, Bt, K, N, N / 32, K / 32, bs};
      bs += E * (N / 32) * (K / 32);
    };
    addW(0, ew0, B_ew0, 512, 1024, 8);
    addW(1, ew1, B_ew1, 1024, 512, 8);
    addW(2, ew2, B_ew2, 512, 256, 8);
    addW(3, gw0, B_gw0, 64, 1024, 1);
    addW(4, gw1, B_gw1, 1024, 512, 1);
    addW(5, gw2, B_gw2, 512, 256, 1);
    prep_w_all<<<dim3(bs), dim3(32, 8), 0, stream>>>(wj);
  }

  auto runGroup = [&](int e0, int cnt, bool withGate){
    SliceArr sa; int nb;
    // L0
    nb = 0; sa.nz = cnt + (withGate ? 1 : 0);
    for (int i = 0; i < cnt; i++){ int e = e0 + i;
      sa.s[i] = {A_obs, B_ew0 + (size_t)e * 1024 * 1024, eb0 + e * 1024,
                 h0buf + (size_t)i * sl0e, nullptr, nullptr, nullptr,
                 1024, 512, 2, 0, nb, 0};
      nb += 4 * 32;
    }
    if (withGate){
      sa.s[cnt] = {A_code, B_gw0, gb0, h0g, nullptr, nullptr, nullptr,
                   1024, 64, 2, 0, nb, 0};
      nb += 4 * 32;
    }
    for (int i = sa.nz; i < 9; i++) sa.s[i] = sa.s[0];
    gemm8p<<<dim3(nb), 512, 0, stream>>>(sa);
    // L1
    nb = 0;
    for (int i = 0; i < cnt; i++){ int e = e0 + i;
      sa.s[i] = {h0buf + (size_t)i * sl0e, B_ew1 + (size_t)e * 512 * 2048, eb1 + e * 512,
                 h1buf + (size_t)i * sl1e, nullptr, nullptr, nullptr,
                 512, 1024, 1, 0, nb, 0};
      nb += 2 * 32;
    }
    if (withGate){
      sa.s[cnt] = {h0g, B_gw1, gb1, h1g, nullptr, nullptr, nullptr,
                   512, 1024, 1, 0, nb, 0};
      nb += 2 * 32;
    }
    gemm8p<<<dim3(nb), 512, 0, stream>>>(sa);
    // L2: experts fused-returns (mode 2); gate f32 h2 (mode 1)
    nb = 0;
    for (int i = 0; i < cnt; i++){ int e = e0 + i;
      sa.s[i] = {h1buf + (size_t)i * sl1e, B_ew2 + (size_t)e * 256 * 1024, eb2 + e * 256,
                 nullptr, ew3 + (size_t)e * 256, eb3 + e, ret,
                 256, 512, 0, 2, nb, e};
      nb += 32;
    }
    if (withGate){
      sa.s[cnt] = {h1g, B_gw2, gb2, h2g, nullptr, nullptr, nullptr,
                   256, 512, 0, 1, nb, 0};
      nb += 32;
    }
    gemm8p<<<dim3(nb), 512, 0, stream>>>(sa);
    if (withGate)
      gate3_softmax<<<dim3(2048), 256, 0, stream>>>(h2g, gw3, gb3, wts);
  };

  if (gateFirst){
    SliceArr sa; sa.nz = 1;
    sa.s[0] = {A_code, B_gw0, gb0, h0g, nullptr, nullptr, nullptr, 1024, 64, 2, 0, 0, 0};
    for (int i = 1; i < 9; i++) sa.s[i] = sa.s[0];
    gemm8p<<<dim3(128), 512, 0, stream>>>(sa);
    sa.s[0] = {h0g, B_gw1, gb1, h1g, nullptr, nullptr, nullptr, 512, 1024, 1, 0, 0, 0};
    gemm8p<<<dim3(64), 512, 0, stream>>>(sa);
    sa.s[0] = {h1g, B_gw2, gb2, h2g, nullptr, nullptr, nullptr, 256, 512, 0, 1, 0, 0};
    gemm8p<<<dim3(32), 512, 0, stream>>>(sa);
    gate3_softmax<<<dim3(2048), 256, 0, stream>>>(h2g, gw3, gb3, wts);
    for (int e = 0; e < 8; e++) runGroup(e, 1, false);
  } else {
    bool first = true;
    for (int e0 = 0; e0 < 8; ){
      int cnt = (8 - e0 < G) ? (8 - e0) : G;
      runGroup(e0, cnt, first);
      first = false;
      e0 += cnt;
    }
  }

  combine<<<dim3(8192 / 256), 256, 0, stream>>>(wts, ret, (float*)d_out);
}